// Round 8
// baseline (147.329 us; speedup 1.0000x reference)
//
#include <hip/hip_runtime.h>
#include <hip/hip_bf16.h>
#include <stdint.h>

// Problem constants: B=2, L=2048, E=1024, H=16, HD=64, G=4.
#define L_SEQ 2048
#define MTOT  4096   // B*L
#define EDIM  1024

typedef __attribute__((ext_vector_type(8))) short bf16x8;   // 8 bf16 (4 VGPRs)
typedef __attribute__((ext_vector_type(4))) float f32x4;
typedef __attribute__((ext_vector_type(4))) float float4v;
typedef __attribute__((ext_vector_type(4))) unsigned short us4;

__device__ __forceinline__ unsigned short f2b(float f) {
    union { float f; unsigned u; } v; v.f = f;
    return (unsigned short)((v.u + 0x7FFFu + ((v.u >> 16) & 1u)) >> 16);  // RNE
}
__device__ __forceinline__ float b2f(unsigned short h) {
    union { unsigned u; float f; } v; v.u = ((unsigned)h) << 16;
    return v.f;
}
__device__ __forceinline__ unsigned cvtpk(float lo, float hi) {   // RNE pack
    unsigned r;
    asm("v_cvt_pk_bf16_f32 %0, %1, %2" : "=v"(r) : "v"(lo), "v"(hi));
    return r;
}
__device__ __forceinline__ void lds16(const void* g, void* l) {
    __builtin_amdgcn_global_load_lds((const __attribute__((address_space(1))) void*)g,
                                     (__attribute__((address_space(3))) void*)l, 16, 0, 0);
}

// ---------------------------------------------------------------------------
// Grid barrier (all 256 blocks resident: 144KB LDS -> 1 block/CU structurally).
// Two-level: 8 group counters (64B apart) x 32 blocks + master count + gen.
// Agent-scope release (threadfence: L2 wb) / acquire (buffer inv) handle
// cross-XCD visibility. State zeroed via hipMemsetAsync before each launch;
// gen comparison is relative, counters self-reset -> reusable across phases.
// ---------------------------------------------------------------------------
__device__ __forceinline__ void gridbar(unsigned* st) {
    __syncthreads();
    if (threadIdx.x == 0) {
        __threadfence();                               // release block's writes
        unsigned* gcnt = st + (blockIdx.x & 7) * 16;
        unsigned* mid  = st + 128;
        unsigned* gen  = st + 129;
        unsigned g0 = __hip_atomic_load(gen, __ATOMIC_RELAXED, __HIP_MEMORY_SCOPE_AGENT);
        unsigned a  = __hip_atomic_fetch_add(gcnt, 1u, __ATOMIC_ACQ_REL, __HIP_MEMORY_SCOPE_AGENT);
        bool done = false;
        if (a == 31u) {                                // last of my 32-group
            unsigned m = __hip_atomic_fetch_add(mid, 1u, __ATOMIC_ACQ_REL, __HIP_MEMORY_SCOPE_AGENT);
            if (m == 7u) {                             // last master: reset+release
                for (int i = 0; i < 8; ++i)
                    __hip_atomic_store(st + i * 16, 0u, __ATOMIC_RELAXED, __HIP_MEMORY_SCOPE_AGENT);
                __hip_atomic_store(mid, 0u, __ATOMIC_RELAXED, __HIP_MEMORY_SCOPE_AGENT);
                __hip_atomic_fetch_add(gen, 1u, __ATOMIC_RELEASE, __HIP_MEMORY_SCOPE_AGENT);
                done = true;
            }
        }
        if (!done) {
            while (__hip_atomic_load(gen, __ATOMIC_ACQUIRE, __HIP_MEMORY_SCOPE_AGENT) == g0)
                __builtin_amdgcn_s_sleep(4);
        }
    }
    __syncthreads();
}

// ---------------------------------------------------------------------------
// GEMM phase (R7-verified): 8-wave K-split, 64x64 wave tiles, gload_lds
// staging, counted-vmcnt 3-buffer pipeline, XOR bank swizzle, XCD remap.
//   TA=1: A staged raw fp32, frags packed via v_cvt_pk_bf16_f32. LDS 144KB.
//   TA=0: A bf16, per-tile source switch (t<tsplit ? Ab0 : Ab1). LDS 96KB.
// OUT_MODE 0: bf16 store. OUT_MODE 1: f32 store + bias[col].
// ---------------------------------------------------------------------------
template <int TA, int OUT_MODE>
__device__ __forceinline__ void gemm_phase(
    uint8_t* sh, int blk,
    const float* __restrict__ Af,
    const unsigned short* __restrict__ Ab0, const unsigned short* __restrict__ Ab1,
    int tsplit,
    const unsigned short* __restrict__ BT,
    unsigned short* __restrict__ Cb, float* __restrict__ Cf,
    const float* __restrict__ bias)
{
    constexpr int ABUF = TA ? 49152 : 32768;   // bytes per buffer (A+B)
    constexpr int ABYT = TA ? 32768 : 16384;   // A bytes within buffer

    // XCD-aware remap (256 blocks, %8==0 -> bijective chunked).
    int wg = (blk & 7) * 32 + (blk >> 3);
    const int m0 = (wg >> 3) * 128, n0 = (wg & 7) * 128;

    const int tid  = threadIdx.x;
    const int wid  = tid >> 6;
    const int lane = tid & 63;
    const int wr   = wid >> 2;
    const int wc   = (wid >> 1) & 1;
    const int kh   = wid & 1;
    const int fr   = lane & 15, fq = lane >> 4;

    f32x4 acc[4][4] = {};

    auto stage = [&](int buf, int t) {
        uint8_t* Abase = sh + buf * ABUF;
        uint8_t* Bbase = Abase + ABYT;
        if (TA) {
            const float* Asrc = Af + (size_t)m0 * EDIM + t * 64;
#pragma unroll
            for (int j = 0; j < 4; ++j) {
                int slot = j * 512 + tid;
                int row = slot >> 4, c = (slot & 15) ^ (row & 15);
                lds16(Asrc + (size_t)row * EDIM + c * 4,
                      Abase + j * 8192 + wid * 1024);
            }
        } else {
            const unsigned short* Asrc =
                (t < tsplit ? Ab0 : Ab1) + (size_t)m0 * EDIM + t * 64;
#pragma unroll
            for (int j = 0; j < 2; ++j) {
                int slot = j * 512 + tid;
                int row = slot >> 3, c = (slot & 7) ^ (row & 7);
                lds16(Asrc + (size_t)row * EDIM + c * 8,
                      Abase + j * 8192 + wid * 1024);
            }
        }
        const unsigned short* Bsrc = BT + (size_t)n0 * EDIM + t * 64;
#pragma unroll
        for (int j = 0; j < 2; ++j) {
            int slot = j * 512 + tid;
            int row = slot >> 3, c = (slot & 7) ^ (row & 7);
            lds16(Bsrc + (size_t)row * EDIM + c * 8,
                  Bbase + j * 8192 + wid * 1024);
        }
    };

    auto compute = [&](int buf) {
        const uint8_t* Abase = sh + buf * ABUF;
        const unsigned short* bs = (const unsigned short*)(Abase + ABYT);
        bf16x8 a[4], b[4];
#pragma unroll
        for (int mi = 0; mi < 4; ++mi) {
            int row = wr * 64 + mi * 16 + fr;
            if (TA) {
                const float* as = (const float*)Abase;
                int c0 = kh * 8 + fq * 2;
                f32x4 lo = *(const f32x4*)(as + row * 64 + ((c0 ^ (row & 15)) * 4));
                f32x4 hi = *(const f32x4*)(as + row * 64 + (((c0 + 1) ^ (row & 15)) * 4));
                union { unsigned u[4]; bf16x8 v; } fu;
                fu.u[0] = cvtpk(lo[0], lo[1]); fu.u[1] = cvtpk(lo[2], lo[3]);
                fu.u[2] = cvtpk(hi[0], hi[1]); fu.u[3] = cvtpk(hi[2], hi[3]);
                a[mi] = fu.v;
            } else {
                const unsigned short* as = (const unsigned short*)Abase;
                a[mi] = *(const bf16x8*)(as + row * 64 + (((kh * 4 + fq) ^ (row & 7)) * 8));
            }
        }
#pragma unroll
        for (int ni = 0; ni < 4; ++ni) {
            int row = wc * 64 + ni * 16 + fr;
            b[ni] = *(const bf16x8*)(bs + row * 64 + (((kh * 4 + fq) ^ (row & 7)) * 8));
        }
#pragma unroll
        for (int mi = 0; mi < 4; ++mi)
#pragma unroll
            for (int ni = 0; ni < 4; ++ni)
                acc[mi][ni] = __builtin_amdgcn_mfma_f32_16x16x32_bf16(a[mi], b[ni], acc[mi][ni], 0, 0, 0);
    };

    const int NT = EDIM >> 6;   // 16 K-tiles
    stage(0, 0);
    stage(1, 1);
    if (TA) asm volatile("s_waitcnt vmcnt(6)" ::: "memory");
    else    asm volatile("s_waitcnt vmcnt(4)" ::: "memory");
    __builtin_amdgcn_s_barrier();
    asm volatile("" ::: "memory");

    for (int t = 0; t < NT; ++t) {
        if (t + 2 < NT) stage((t + 2) % 3, t + 2);
        compute(t % 3);
        if (t + 1 < NT) {
            if (t + 2 < NT) {
                if (TA) asm volatile("s_waitcnt vmcnt(6)" ::: "memory");
                else    asm volatile("s_waitcnt vmcnt(4)" ::: "memory");
            } else {
                asm volatile("s_waitcnt vmcnt(0)" ::: "memory");
            }
            __builtin_amdgcn_s_barrier();
            asm volatile("" ::: "memory");
        }
    }

    // ---- K-split merge: kh=1 dumps partials to LDS, kh=0 adds & stores. ----
    __syncthreads();
    float* Mg = (float*)sh;
    const int mgbase = (wr * 2 + wc) * 4096;
    if (kh) {
#pragma unroll
        for (int mi = 0; mi < 4; ++mi)
#pragma unroll
            for (int ni = 0; ni < 4; ++ni) {
                int col = ni * 16 + fr;
                int adr = mgbase + col * 64 + (((mi * 4 + fq) ^ (col & 15)) << 2);
                *(f32x4*)(Mg + adr) = acc[mi][ni];
            }
    }
    __syncthreads();
    if (!kh) {
        // epilogue: C/D layout col=lane&15, row=(lane>>4)*4+j  [m89-verified]
#pragma unroll
        for (int mi = 0; mi < 4; ++mi) {
#pragma unroll
            for (int ni = 0; ni < 4; ++ni) {
                int col = ni * 16 + fr;
                int adr = mgbase + col * 64 + (((mi * 4 + fq) ^ (col & 15)) << 2);
                f32x4 p = *(const f32x4*)(Mg + adr);
                int gcol = n0 + wc * 64 + col;
                int rowb = m0 + wr * 64 + mi * 16 + fq * 4;
#pragma unroll
                for (int j = 0; j < 4; ++j) {
                    float v = acc[mi][ni][j] + p[j];
                    if (OUT_MODE == 0) {
                        Cb[(size_t)(rowb + j) * EDIM + gcol] = f2b(v);
                    } else {
                        Cf[(size_t)(rowb + j) * EDIM + gcol] = v + bias[gcol];
                    }
                }
            }
        }
    }
    __syncthreads();   // sh reuse safe for next phase
}

// ---------------------------------------------------------------------------
// Megakernel: W-prep -> [bar] -> gemm1 -> [bar] -> conv -> [bar] -> gemm2.
// 256 blocks x 512 threads, 144KB LDS (1 block/CU -> barrier-safe).
// ---------------------------------------------------------------------------
__global__ __launch_bounds__(512, 2) void mega_kernel(
    const float* __restrict__ x, const float* __restrict__ Wq,
    const float* __restrict__ Wv, const float* __restrict__ Wo,
    const float* __restrict__ bo,
    const float* __restrict__ q3w, const float* __restrict__ q3b,
    const float* __restrict__ v3w, const float* __restrict__ v3b,
    const float* __restrict__ q5w, const float* __restrict__ q5b,
    const float* __restrict__ v5w, const float* __restrict__ v5b,
    const float* __restrict__ q7w, const float* __restrict__ q7b,
    const float* __restrict__ v7w, const float* __restrict__ v7b,
    unsigned short* __restrict__ W1b, unsigned short* __restrict__ Wob,
    unsigned short* __restrict__ T, unsigned short* __restrict__ V,
    float* __restrict__ H, float* __restrict__ Beff, float* __restrict__ Corr,
    unsigned* __restrict__ bar, float* __restrict__ out)
{
    __shared__ uint8_t sh[3 * 49152];   // 144KB
    const int gtid = blockIdx.x * 512 + threadIdx.x;   // [0, 131072)

    // ---------------- phase W: weight convert + taps ----------------
#pragma unroll
    for (int r = 0; r < 2; ++r) {
        int j = (gtid * 2 + r) * 4;                    // quad offset [0, 1M)
        int row = j >> 10;
        const float* s1 = (row < 256) ? Wv : Wq;       // stitched W1
        float4v v1 = *(const float4v*)(s1 + j);
        us4 o1;
        o1[0] = f2b(v1[0]); o1[1] = f2b(v1[1]); o1[2] = f2b(v1[2]); o1[3] = f2b(v1[3]);
        *(us4*)(W1b + j) = o1;
        float4v v2 = *(const float4v*)(Wo + j);
        us4 o2;
        o2[0] = f2b(v2[0]); o2[1] = f2b(v2[1]); o2[2] = f2b(v2[2]); o2[3] = f2b(v2[3]);
        *(us4*)(Wob + j) = o2;
    }
    if (gtid < 768) {
        // taps: compose the two causal depthwise convs per channel.
        //   dwconv taps h[i] = w[k-1-i]; chain h = hq (*) hv (len 2k-1<=13),
        //   beff = vb + qb*sum(vw); boundary (l<k-1): intermediate zero-pad
        //   drops qb for taps i>l -> Corr[l][ch] = qb*sum_{i=l+1..} hv[i].
        int ch = gtid;
        int g = ch >> 8, d = ch & 63, k = 3 + 2 * g;
        const float* qw = (g == 0) ? q3w : (g == 1) ? q5w : q7w;
        const float* qb = (g == 0) ? q3b : (g == 1) ? q5b : q7b;
        const float* vw = (g == 0) ? v3w : (g == 1) ? v5w : v7w;
        const float* vb = (g == 0) ? v3b : (g == 1) ? v5b : v7b;
        float hq[7], hv[7];
        for (int i = 0; i < 7; ++i) { hq[i] = 0.f; hv[i] = 0.f; }
        for (int i = 0; i < k; ++i) {
            hq[i] = qw[d * k + (k - 1 - i)];
            hv[i] = vw[d * k + (k - 1 - i)];
        }
        float h[13];
        for (int i = 0; i < 13; ++i) h[i] = 0.f;
        for (int a = 0; a < 7; ++a)
            for (int b = 0; b < 7; ++b)
                h[a + b] += hq[a] * hv[b];
        for (int i = 0; i < 13; ++i) H[i * 768 + ch] = h[i];
        float sv = 0.f;
        for (int j = 0; j < k; ++j) sv += vw[d * k + j];
        Beff[ch] = qb[d] * sv + vb[d];
        for (int l = 0; l < 6; ++l) {
            float s2 = 0.f;
            for (int i = l + 1; i < 7; ++i) s2 += hv[i];
            Corr[l * 768 + ch] = qb[d] * s2;
        }
    }
    gridbar(bar);

    // ---------------- phase G1: T = x @ W1^T (A raw fp32) ----------------
    gemm_phase<1, 0>(sh, blockIdx.x, x, nullptr, nullptr, 0,
                     W1b, T, nullptr, nullptr);
    gridbar(bar);

    // ---------------- phase C: causal FIR, cols 256..1023 ----------------
#pragma unroll
    for (int it = 0; it < 3; ++it) {
        unsigned w = (unsigned)it * 131072u + (unsigned)gtid;  // [0, 393216)
        unsigned rp = w / 192u;
        int c4 = (int)(w - rp * 192u);
        int m  = (int)rp * 2;
        int ch = c4 * 4;
        int e0 = 256 + ch;
        const unsigned short* tp = T + (size_t)m * EDIM + e0;
        unsigned short*       vp = V + (size_t)m * EDIM + e0;
        int l = m & (L_SEQ - 1);
        float4v b4 = *(const float4v*)(Beff + ch);
        float4v acc0 = b4, acc1 = b4;
        {
            float4v h = *(const float4v*)(H + ch);
            us4 t = *(const us4*)(tp + EDIM);
            acc1[0] += h[0] * b2f(t[0]); acc1[1] += h[1] * b2f(t[1]);
            acc1[2] += h[2] * b2f(t[2]); acc1[3] += h[3] * b2f(t[3]);
        }
        int ni = (l < 12) ? l : 12;
        for (int i = 0; i <= ni; ++i) {
            us4 t = *(const us4*)(tp - (size_t)i * EDIM);
            float4v h0 = *(const float4v*)(H + i * 768 + ch);
            acc0[0] += h0[0] * b2f(t[0]); acc0[1] += h0[1] * b2f(t[1]);
            acc0[2] += h0[2] * b2f(t[2]); acc0[3] += h0[3] * b2f(t[3]);
            if (i < 12) {
                float4v h1 = *(const float4v*)(H + (i + 1) * 768 + ch);
                acc1[0] += h1[0] * b2f(t[0]); acc1[1] += h1[1] * b2f(t[1]);
                acc1[2] += h1[2] * b2f(t[2]); acc1[3] += h1[3] * b2f(t[3]);
            }
        }
        if (l < 6) {
            float4v c = *(const float4v*)(Corr + l * 768 + ch);
            acc0[0] -= c[0]; acc0[1] -= c[1]; acc0[2] -= c[2]; acc0[3] -= c[3];
        }
        if (l + 1 < 6) {
            float4v c = *(const float4v*)(Corr + (l + 1) * 768 + ch);
            acc1[0] -= c[0]; acc1[1] -= c[1]; acc1[2] -= c[2]; acc1[3] -= c[3];
        }
        us4 o0, o1;
        o0[0] = f2b(acc0[0]); o0[1] = f2b(acc0[1]); o0[2] = f2b(acc0[2]); o0[3] = f2b(acc0[3]);
        o1[0] = f2b(acc1[0]); o1[1] = f2b(acc1[1]); o1[2] = f2b(acc1[2]); o1[3] = f2b(acc1[3]);
        *(us4*)vp = o0;
        *(us4*)(vp + EDIM) = o1;
    }
    gridbar(bar);

    // ------- phase G2: out = [T[:,:256] | V[:,256:]] @ Wo^T + bo -------
    gemm_phase<0, 1>(sh, blockIdx.x, nullptr, T, V, 4,
                     Wob, nullptr, out, bo);
}

// ---------------------------------------------------------------------------
extern "C" void kernel_launch(void* const* d_in, const int* in_sizes, int n_in,
                              void* d_out, int out_size, void* d_ws, size_t ws_size,
                              hipStream_t stream)
{
    const float* x  = (const float*)d_in[0];
    const float* Wq = (const float*)d_in[1];
    // d_in[2] = Wk (dead: attention output is multiplied by 0.0)
    const float* Wv = (const float*)d_in[3];
    const float* Wo = (const float*)d_in[4];
    const float* bo = (const float*)d_in[5];

    uint8_t* ws = (uint8_t*)d_ws;
    unsigned short* W1b = (unsigned short*)(ws);                    //  2 MB
    unsigned short* Wob = (unsigned short*)(ws + (2u  << 20));      //  2 MB
    unsigned short* T   = (unsigned short*)(ws + (4u  << 20));      //  8 MB
    unsigned short* V   = (unsigned short*)(ws + (12u << 20));      //  8 MB
    float* H    = (float*)(ws + (20u << 20));                        // 40 KB
    float* Beff = (float*)(ws + (20u << 20) + (64u << 10));          //  3 KB
    float* Corr = (float*)(ws + (20u << 20) + (96u << 10));          // 18 KB
    unsigned* bar = (unsigned*)(ws + (21u << 20));                   // 640 B

    hipMemsetAsync(bar, 0, 1024, stream);   // barrier state: zero each replay

    mega_kernel<<<256, 512, 0, stream>>>(
        x, Wq, Wv, Wo, bo,
        (const float*)d_in[6],  (const float*)d_in[7],
        (const float*)d_in[10], (const float*)d_in[11],
        (const float*)d_in[12], (const float*)d_in[13],
        (const float*)d_in[16], (const float*)d_in[17],
        (const float*)d_in[18], (const float*)d_in[19],
        (const float*)d_in[22], (const float*)d_in[23],
        W1b, Wob, T, V, H, Beff, Corr, bar, (float*)d_out);
}

// Round 9
// 60.019 us; speedup vs baseline: 2.4547x; 2.4547x over previous
//
#include <hip/hip_runtime.h>
#include <hip/hip_bf16.h>
#include <stdint.h>

// Problem constants: B=2, L=2048, E=1024, H=16, HD=64, G=4.
#define L_SEQ 2048
#define MTOT  4096   // B*L
#define EDIM  1024

typedef __attribute__((ext_vector_type(8))) short bf16x8;   // 8 bf16 (4 VGPRs)
typedef __attribute__((ext_vector_type(4))) float f32x4;
typedef __attribute__((ext_vector_type(4))) float float4v;
typedef __attribute__((ext_vector_type(4))) unsigned short us4;

__device__ __forceinline__ unsigned short f2b(float f) {
    union { float f; unsigned u; } v; v.f = f;
    return (unsigned short)((v.u + 0x7FFFu + ((v.u >> 16) & 1u)) >> 16);  // RNE
}
__device__ __forceinline__ float b2f(unsigned short h) {
    union { unsigned u; float f; } v; v.u = ((unsigned)h) << 16;
    return v.f;
}
__device__ __forceinline__ unsigned cvtpk(float lo, float hi) {   // RNE pack
    unsigned r;
    asm("v_cvt_pk_bf16_f32 %0, %1, %2" : "=v"(r) : "v"(lo), "v"(hi));
    return r;
}
__device__ __forceinline__ void lds16(const void* g, void* l) {
    __builtin_amdgcn_global_load_lds((const __attribute__((address_space(1))) void*)g,
                                     (__attribute__((address_space(3))) void*)l, 16, 0, 0);
}

// ---------------------------------------------------------------------------
// wprep: convert W1 (stitched [Wv rows 0..255 ; Wq rows 256..1023]) and Wo
//        to bf16. Blocks >= 2048 compute the composed FIR taps.  (R7-verified)
// ---------------------------------------------------------------------------
__global__ __launch_bounds__(256) void wprep_kernel(
    const float* __restrict__ Wq, const float* __restrict__ Wv,
    const float* __restrict__ Wo,
    unsigned short* __restrict__ W1b, unsigned short* __restrict__ Wob,
    const float* __restrict__ q3w, const float* __restrict__ q3b,
    const float* __restrict__ v3w, const float* __restrict__ v3b,
    const float* __restrict__ q5w, const float* __restrict__ q5b,
    const float* __restrict__ v5w, const float* __restrict__ v5b,
    const float* __restrict__ q7w, const float* __restrict__ q7b,
    const float* __restrict__ v7w, const float* __restrict__ v7b,
    float* __restrict__ H, float* __restrict__ Beff, float* __restrict__ Corr)
{
    if (blockIdx.x >= 2048) {
        // taps: dwconv taps h[i]=w[k-1-i]; chain h = hq (*) hv (len 2k-1<=13),
        // beff = vb + qb*sum(vw); boundary (l<k-1): intermediate zero-pad
        // drops qb for taps i>l -> Corr[l][ch] = qb*sum_{i=l+1..} hv[i].
        int ch = (blockIdx.x - 2048) * 256 + threadIdx.x;   // [0,768)
        int g = ch >> 8, d = ch & 63, k = 3 + 2 * g;
        const float* qw = (g == 0) ? q3w : (g == 1) ? q5w : q7w;
        const float* qb = (g == 0) ? q3b : (g == 1) ? q5b : q7b;
        const float* vw = (g == 0) ? v3w : (g == 1) ? v5w : v7w;
        const float* vb = (g == 0) ? v3b : (g == 1) ? v5b : v7b;

        float hq[7], hv[7];
        for (int i = 0; i < 7; ++i) { hq[i] = 0.f; hv[i] = 0.f; }
        for (int i = 0; i < k; ++i) {
            hq[i] = qw[d * k + (k - 1 - i)];
            hv[i] = vw[d * k + (k - 1 - i)];
        }
        float h[13];
        for (int i = 0; i < 13; ++i) h[i] = 0.f;
        for (int a = 0; a < 7; ++a)
            for (int b = 0; b < 7; ++b)
                h[a + b] += hq[a] * hv[b];
        for (int i = 0; i < 13; ++i) H[i * 768 + ch] = h[i];

        float sv = 0.f;
        for (int j = 0; j < k; ++j) sv += vw[d * k + j];
        Beff[ch] = qb[d] * sv + vb[d];

        for (int l = 0; l < 6; ++l) {
            float s2 = 0.f;
            for (int i = l + 1; i < 7; ++i) s2 += hv[i];
            Corr[l * 768 + ch] = qb[d] * s2;
        }
        return;
    }
    const int WQ = (EDIM * EDIM) / 4;   // 262,144 quads per matrix
    int i = blockIdx.x * 256 + threadIdx.x;
    const float* src;
    unsigned short* dst;
    int j;
    if (i < WQ) {
        j = i * 4;
        int row = j >> 10;                 // /1024
        src = (row < 256) ? Wv : Wq;       // stitched W1
        dst = W1b;
    } else {
        j = (i - WQ) * 4; src = Wo; dst = Wob;
    }
    float4v v = *(const float4v*)(src + j);
    us4 o;
    o[0] = f2b(v[0]); o[1] = f2b(v[1]); o[2] = f2b(v[2]); o[3] = f2b(v[3]);
    *(us4*)(dst + j) = o;
}

// ---------------------------------------------------------------------------
// GEMM, 64x64 tiles for TLP: C[M=4096,N=1024] = A * BT^T.
//   BM=BN=64, 256 thr = 4 waves (2x2), wave tile 32x32, acc 2x2.
//   Grid (16,64) = 1024 blocks -> 3-4 blocks/CU: cross-block overlap hides
//   per-tile barrier/wait stalls (m114 mechanism; 128^2 grid gave 1/CU).
//   TA=1 (gemm1): A raw fp32 (x), BK=32, bufs 12KB x3 = 36KB -> 4 blocks/CU
//                 (launch_bounds(256,4) caps VGPR 128). Frags cvt_pk'd.
//   TA=0 (gemm2): A bf16 w/ per-tile src switch (t<tsplit ? Ab0 : Ab1),
//                 BK=64, bufs 16KB x3 = 48KB -> 3 blocks/CU.
//   3-buffer counted-vmcnt pipeline (depth 2, steady wait vmcnt(LPT):
//   3 loads/thread TA=1, 4 TA=0). Never vmcnt(0) mid-loop.
//   Swizzles (both-sides XOR): A fp32 8-chunk rows ^(row&7); bf16 BK=64 rows
//   8 chunks ^(row&7); bf16 BK=32 rows 4 chunks ^(row&3). XCD remap:
//   1024 blocks, chunk of 128 per XCD spans 512 M-rows (A-panel L2-fits).
// OUT_MODE 0: bf16 store. OUT_MODE 1: f32 store + bias[col].
// ---------------------------------------------------------------------------
template <int TA, int OUT_MODE>
__global__ __launch_bounds__(256, TA ? 4 : 3) void gemm64(
    const float* __restrict__ Af,
    const unsigned short* __restrict__ Ab0, const unsigned short* __restrict__ Ab1,
    int tsplit,
    const unsigned short* __restrict__ BT,
    unsigned short* __restrict__ Cb, float* __restrict__ Cf,
    const float* __restrict__ bias)
{
    constexpr int BK   = TA ? 32 : 64;
    constexpr int NT   = 1024 / BK;           // 32 or 16 K-tiles
    constexpr int ABYT = 8192;                // 64x32xf32 or 64x64xbf16 = 8KB
    constexpr int BBYT = TA ? 4096 : 8192;    // 64xBK bf16
    constexpr int BUF  = ABYT + BBYT;
    __shared__ uint8_t sh[3 * BUF];

    // XCD remap: orig%8 = hw XCD; chunk of 128 contiguous wg per XCD.
    int orig = blockIdx.y * 16 + blockIdx.x;
    int wg   = (orig & 7) * 128 + (orig >> 3);
    const int m0 = (wg >> 4) * 64, n0 = (wg & 15) * 64;

    const int tid  = threadIdx.x;
    const int wid  = tid >> 6;
    const int lane = tid & 63;
    const int wr   = wid >> 1, wc = wid & 1;      // 2x2 waves, 32x32 tiles
    const int fr   = lane & 15, fq = lane >> 4;

    f32x4 acc[2][2] = {};

    auto stage = [&](int buf, int t) {
        uint8_t* Abase = sh + buf * BUF;
        uint8_t* Bbase = Abase + ABYT;
        if (TA) {
            // A fp32 64x32: 512 chunks (8/row), 2/thread
            const float* Asrc = Af + (size_t)m0 * EDIM + t * 32;
#pragma unroll
            for (int j = 0; j < 2; ++j) {
                int slot = j * 256 + tid;
                int row = slot >> 3, c = (slot & 7) ^ (row & 7);
                lds16(Asrc + (size_t)row * EDIM + c * 4,
                      Abase + j * 4096 + wid * 1024);
            }
            // B bf16 64x32: 256 chunks (4/row), 1/thread
            const unsigned short* Bsrc = BT + (size_t)n0 * EDIM + t * 32;
            {
                int row = tid >> 2, c = (tid & 3) ^ (row & 3);
                lds16(Bsrc + (size_t)row * EDIM + c * 8, Bbase + wid * 1024);
            }
        } else {
            // A bf16 64x64: 512 chunks (8/row), 2/thread
            const unsigned short* Asrc =
                (t < tsplit ? Ab0 : Ab1) + (size_t)m0 * EDIM + t * 64;
#pragma unroll
            for (int j = 0; j < 2; ++j) {
                int slot = j * 256 + tid;
                int row = slot >> 3, c = (slot & 7) ^ (row & 7);
                lds16(Asrc + (size_t)row * EDIM + c * 8,
                      Abase + j * 4096 + wid * 1024);
            }
            // B bf16 64x64: 512 chunks, 2/thread
            const unsigned short* Bsrc = BT + (size_t)n0 * EDIM + t * 64;
#pragma unroll
            for (int j = 0; j < 2; ++j) {
                int slot = j * 256 + tid;
                int row = slot >> 3, c = (slot & 7) ^ (row & 7);
                lds16(Bsrc + (size_t)row * EDIM + c * 8,
                      Bbase + j * 4096 + wid * 1024);
            }
        }
    };

    auto compute = [&](int buf) {
        const uint8_t* Abase = sh + buf * BUF;
        if (TA) {
            const float* as = (const float*)Abase;                 // [64][32]
            const unsigned short* bs = (const unsigned short*)(Abase + ABYT);
            bf16x8 a[2], b[2];
#pragma unroll
            for (int mi = 0; mi < 2; ++mi) {
                int row = wr * 32 + mi * 16 + fr;
                int c0 = fq * 2;
                f32x4 lo = *(const f32x4*)(as + row * 32 + ((c0 ^ (row & 7)) * 4));
                f32x4 hi = *(const f32x4*)(as + row * 32 + (((c0 + 1) ^ (row & 7)) * 4));
                union { unsigned u[4]; bf16x8 v; } fu;
                fu.u[0] = cvtpk(lo[0], lo[1]); fu.u[1] = cvtpk(lo[2], lo[3]);
                fu.u[2] = cvtpk(hi[0], hi[1]); fu.u[3] = cvtpk(hi[2], hi[3]);
                a[mi] = fu.v;
            }
#pragma unroll
            for (int ni = 0; ni < 2; ++ni) {
                int row = wc * 32 + ni * 16 + fr;
                b[ni] = *(const bf16x8*)(bs + row * 32 + (((fq) ^ (row & 3)) * 8));
            }
#pragma unroll
            for (int mi = 0; mi < 2; ++mi)
#pragma unroll
                for (int ni = 0; ni < 2; ++ni)
                    acc[mi][ni] = __builtin_amdgcn_mfma_f32_16x16x32_bf16(a[mi], b[ni], acc[mi][ni], 0, 0, 0);
        } else {
            const unsigned short* as = (const unsigned short*)Abase;  // [64][64]
            const unsigned short* bs = (const unsigned short*)(Abase + ABYT);
#pragma unroll
            for (int s = 0; s < 2; ++s) {
                bf16x8 a[2], b[2];
#pragma unroll
                for (int mi = 0; mi < 2; ++mi) {
                    int row = wr * 32 + mi * 16 + fr;
                    a[mi] = *(const bf16x8*)(as + row * 64 + (((s * 4 + fq) ^ (row & 7)) * 8));
                }
#pragma unroll
                for (int ni = 0; ni < 2; ++ni) {
                    int row = wc * 32 + ni * 16 + fr;
                    b[ni] = *(const bf16x8*)(bs + row * 64 + (((s * 4 + fq) ^ (row & 7)) * 8));
                }
#pragma unroll
                for (int mi = 0; mi < 2; ++mi)
#pragma unroll
                    for (int ni = 0; ni < 2; ++ni)
                        acc[mi][ni] = __builtin_amdgcn_mfma_f32_16x16x32_bf16(a[mi], b[ni], acc[mi][ni], 0, 0, 0);
            }
        }
    };

    stage(0, 0);
    stage(1, 1);
    if (TA) asm volatile("s_waitcnt vmcnt(3)" ::: "memory");   // tile 0 landed
    else    asm volatile("s_waitcnt vmcnt(4)" ::: "memory");
    __builtin_amdgcn_s_barrier();
    asm volatile("" ::: "memory");

    for (int t = 0; t < NT; ++t) {
        if (t + 2 < NT) stage((t + 2) % 3, t + 2);
        compute(t % 3);
        if (t + 1 < NT) {
            if (t + 2 < NT) {
                if (TA) asm volatile("s_waitcnt vmcnt(3)" ::: "memory");
                else    asm volatile("s_waitcnt vmcnt(4)" ::: "memory");
            } else {
                asm volatile("s_waitcnt vmcnt(0)" ::: "memory");  // drain tail
            }
            __builtin_amdgcn_s_barrier();
            asm volatile("" ::: "memory");
        }
    }

    // epilogue: C/D layout col=lane&15, row=(lane>>4)*4+j  [m89-verified]
#pragma unroll
    for (int mi = 0; mi < 2; ++mi) {
#pragma unroll
        for (int ni = 0; ni < 2; ++ni) {
            int col  = n0 + wc * 32 + ni * 16 + fr;
            int rowb = m0 + wr * 32 + mi * 16 + fq * 4;
#pragma unroll
            for (int j = 0; j < 4; ++j) {
                float v = acc[mi][ni][j];
                if (OUT_MODE == 0) {
                    Cb[(size_t)(rowb + j) * EDIM + col] = f2b(v);
                } else {
                    Cf[(size_t)(rowb + j) * EDIM + col] = v + bias[col];
                }
            }
        }
    }
}

// ---------------------------------------------------------------------------
// conv: causal FIR on cols 256..1023 (v0 cols read from T by gemm2's t<4
// tiles). Thread: 4 channels x 2 consecutive positions.  (R7-verified)
// ---------------------------------------------------------------------------
__global__ __launch_bounds__(256) void conv_kernel(
    const unsigned short* __restrict__ T, unsigned short* __restrict__ V,
    const float* __restrict__ H, const float* __restrict__ Beff,
    const float* __restrict__ Corr)
{
    unsigned w  = blockIdx.x * 256 + threadIdx.x;   // 2048 rowpairs x 192 quads
    unsigned rp = w / 192u;
    int c4 = (int)(w - rp * 192u);
    int m  = (int)rp * 2;                           // pair never crosses batch
    int ch = c4 * 4;                                // [0,768)
    int e0 = 256 + ch;
    const unsigned short* tp = T + (size_t)m * EDIM + e0;
    unsigned short*       vp = V + (size_t)m * EDIM + e0;
    int l  = m & (L_SEQ - 1);
    float4v b4 = *(const float4v*)(Beff + ch);
    float4v acc0 = b4, acc1 = b4;

    {
        float4v h = *(const float4v*)(H + ch);      // H[0], row m+1
        us4 t = *(const us4*)(tp + EDIM);
        acc1[0] += h[0] * b2f(t[0]); acc1[1] += h[1] * b2f(t[1]);
        acc1[2] += h[2] * b2f(t[2]); acc1[3] += h[3] * b2f(t[3]);
    }
    int ni = (l < 12) ? l : 12;
    for (int i = 0; i <= ni; ++i) {                 // row m-i, taps h[i]/h[i+1]
        us4 t = *(const us4*)(tp - (size_t)i * EDIM);
        float4v h0 = *(const float4v*)(H + i * 768 + ch);
        acc0[0] += h0[0] * b2f(t[0]); acc0[1] += h0[1] * b2f(t[1]);
        acc0[2] += h0[2] * b2f(t[2]); acc0[3] += h0[3] * b2f(t[3]);
        if (i < 12) {
            float4v h1 = *(const float4v*)(H + (i + 1) * 768 + ch);
            acc1[0] += h1[0] * b2f(t[0]); acc1[1] += h1[1] * b2f(t[1]);
            acc1[2] += h1[2] * b2f(t[2]); acc1[3] += h1[3] * b2f(t[3]);
        }
    }
    if (l < 6) {   // bias boundary correction (intermediate zero-padding)
        float4v c = *(const float4v*)(Corr + l * 768 + ch);
        acc0[0] -= c[0]; acc0[1] -= c[1]; acc0[2] -= c[2]; acc0[3] -= c[3];
    }
    if (l + 1 < 6) {
        float4v c = *(const float4v*)(Corr + (l + 1) * 768 + ch);
        acc1[0] -= c[0]; acc1[1] -= c[1]; acc1[2] -= c[2]; acc1[3] -= c[3];
    }
    us4 o0, o1;
    o0[0] = f2b(acc0[0]); o0[1] = f2b(acc0[1]); o0[2] = f2b(acc0[2]); o0[3] = f2b(acc0[3]);
    o1[0] = f2b(acc1[0]); o1[1] = f2b(acc1[1]); o1[2] = f2b(acc1[2]); o1[3] = f2b(acc1[3]);
    *(us4*)vp = o0;
    *(us4*)(vp + EDIM) = o1;
}

// ---------------------------------------------------------------------------
extern "C" void kernel_launch(void* const* d_in, const int* in_sizes, int n_in,
                              void* d_out, int out_size, void* d_ws, size_t ws_size,
                              hipStream_t stream)
{
    const float* x  = (const float*)d_in[0];
    const float* Wq = (const float*)d_in[1];
    // d_in[2] = Wk (dead: attention output is multiplied by 0.0)
    const float* Wv = (const float*)d_in[3];
    const float* Wo = (const float*)d_in[4];
    const float* bo = (const float*)d_in[5];

    uint8_t* ws = (uint8_t*)d_ws;
    unsigned short* W1b = (unsigned short*)(ws);                    //  2 MB
    unsigned short* Wob = (unsigned short*)(ws + (2u  << 20));      //  2 MB
    unsigned short* T   = (unsigned short*)(ws + (4u  << 20));      //  8 MB
    unsigned short* V   = (unsigned short*)(ws + (12u << 20));      //  8 MB
    float* H    = (float*)(ws + (20u << 20));                        // 40 KB
    float* Beff = (float*)(ws + (20u << 20) + (64u << 10));          //  3 KB
    float* Corr = (float*)(ws + (20u << 20) + (96u << 10));          // 18 KB

    wprep_kernel<<<2051, 256, 0, stream>>>(
        Wq, Wv, Wo, W1b, Wob,
        (const float*)d_in[6],  (const float*)d_in[7],
        (const float*)d_in[10], (const float*)d_in[11],
        (const float*)d_in[12], (const float*)d_in[13],
        (const float*)d_in[16], (const float*)d_in[17],
        (const float*)d_in[18], (const float*)d_in[19],
        (const float*)d_in[22], (const float*)d_in[23],
        H, Beff, Corr);

    dim3 gg(EDIM / 64, MTOT / 64);   // (16, 64) = 1024 blocks, 3-4 per CU
    // gemm1: T = x @ W1^T, A read as raw fp32 (prep fused away), BK=32
    gemm64<1, 0><<<gg, 256, 0, stream>>>(x, nullptr, nullptr, 0,
                                         W1b, T, nullptr, nullptr);

    conv_kernel<<<1536, 256, 0, stream>>>(T, V, H, Beff, Corr);

    // gemm2: out = [T[:, :256] | V[:, 256:]] @ Wo^T + bo  (tsplit=4), BK=64
    gemm64<0, 1><<<gg, 256, 0, stream>>>(nullptr, T, V, 4,
                                         Wob, nullptr, (float*)d_out, bo);
}

// Round 10
// 53.781 us; speedup vs baseline: 2.7394x; 1.1160x over previous
//
#include <hip/hip_runtime.h>
#include <hip/hip_bf16.h>
#include <stdint.h>

// Problem constants: B=2, L=2048, E=1024, H=16, HD=64, G=4.
#define L_SEQ 2048
#define MTOT  4096   // B*L
#define EDIM  1024

typedef __attribute__((ext_vector_type(8))) short bf16x8;    // 8 bf16 (4 VGPRs)
typedef __attribute__((ext_vector_type(4))) float f32x4;
typedef __attribute__((ext_vector_type(16))) float f32x16;   // 32x32 MFMA acc
typedef __attribute__((ext_vector_type(4))) float float4v;
typedef __attribute__((ext_vector_type(4))) unsigned short us4;

__device__ __forceinline__ unsigned short f2b(float f) {
    union { float f; unsigned u; } v; v.f = f;
    return (unsigned short)((v.u + 0x7FFFu + ((v.u >> 16) & 1u)) >> 16);  // RNE
}
__device__ __forceinline__ float b2f(unsigned short h) {
    union { unsigned u; float f; } v; v.u = ((unsigned)h) << 16;
    return v.f;
}
__device__ __forceinline__ unsigned cvtpk(float lo, float hi) {   // RNE pack
    unsigned r;
    asm("v_cvt_pk_bf16_f32 %0, %1, %2" : "=v"(r) : "v"(lo), "v"(hi));
    return r;
}
__device__ __forceinline__ void lds16(const void* g, void* l) {
    __builtin_amdgcn_global_load_lds((const __attribute__((address_space(1))) void*)g,
                                     (__attribute__((address_space(3))) void*)l, 16, 0, 0);
}

// ---------------------------------------------------------------------------
// wprep: convert W1 (stitched [Wv rows 0..255 ; Wq rows 256..1023]) and Wo
//        to bf16. Blocks >= 2048 compute the composed FIR taps.  (R7-verified)
// ---------------------------------------------------------------------------
__global__ __launch_bounds__(256) void wprep_kernel(
    const float* __restrict__ Wq, const float* __restrict__ Wv,
    const float* __restrict__ Wo,
    unsigned short* __restrict__ W1b, unsigned short* __restrict__ Wob,
    const float* __restrict__ q3w, const float* __restrict__ q3b,
    const float* __restrict__ v3w, const float* __restrict__ v3b,
    const float* __restrict__ q5w, const float* __restrict__ q5b,
    const float* __restrict__ v5w, const float* __restrict__ v5b,
    const float* __restrict__ q7w, const float* __restrict__ q7b,
    const float* __restrict__ v7w, const float* __restrict__ v7b,
    float* __restrict__ H, float* __restrict__ Beff, float* __restrict__ Corr)
{
    if (blockIdx.x >= 2048) {
        // taps: dwconv taps h[i]=w[k-1-i]; chain h = hq (*) hv (len 2k-1<=13),
        // beff = vb + qb*sum(vw); boundary (l<k-1): intermediate zero-pad
        // drops qb for taps i>l -> Corr[l][ch] = qb*sum_{i=l+1..} hv[i].
        int ch = (blockIdx.x - 2048) * 256 + threadIdx.x;   // [0,768)
        int g = ch >> 8, d = ch & 63, k = 3 + 2 * g;
        const float* qw = (g == 0) ? q3w : (g == 1) ? q5w : q7w;
        const float* qb = (g == 0) ? q3b : (g == 1) ? q5b : q7b;
        const float* vw = (g == 0) ? v3w : (g == 1) ? v5w : v7w;
        const float* vb = (g == 0) ? v3b : (g == 1) ? v5b : v7b;

        float hq[7], hv[7];
        for (int i = 0; i < 7; ++i) { hq[i] = 0.f; hv[i] = 0.f; }
        for (int i = 0; i < k; ++i) {
            hq[i] = qw[d * k + (k - 1 - i)];
            hv[i] = vw[d * k + (k - 1 - i)];
        }
        float h[13];
        for (int i = 0; i < 13; ++i) h[i] = 0.f;
        for (int a = 0; a < 7; ++a)
            for (int b = 0; b < 7; ++b)
                h[a + b] += hq[a] * hv[b];
        for (int i = 0; i < 13; ++i) H[i * 768 + ch] = h[i];

        float sv = 0.f;
        for (int j = 0; j < k; ++j) sv += vw[d * k + j];
        Beff[ch] = qb[d] * sv + vb[d];

        for (int l = 0; l < 6; ++l) {
            float s2 = 0.f;
            for (int i = l + 1; i < 7; ++i) s2 += hv[i];
            Corr[l * 768 + ch] = qb[d] * s2;
        }
        return;
    }
    const int WQ = (EDIM * EDIM) / 4;   // 262,144 quads per matrix
    int i = blockIdx.x * 256 + threadIdx.x;
    const float* src;
    unsigned short* dst;
    int j;
    if (i < WQ) {
        j = i * 4;
        int row = j >> 10;                 // /1024
        src = (row < 256) ? Wv : Wq;       // stitched W1
        dst = W1b;
    } else {
        j = (i - WQ) * 4; src = Wo; dst = Wob;
    }
    float4v v = *(const float4v*)(src + j);
    us4 o;
    o[0] = f2b(v[0]); o[1] = f2b(v[1]); o[2] = f2b(v[2]); o[3] = f2b(v[3]);
    *(us4*)(dst + j) = o;
}

// ---------------------------------------------------------------------------
// GEMM (R7 structure + 32x32x16 MFMA): C[4096,1024] = A * BT^T.
//   BM=BN=128, BK=64, 512 thr = 8 waves: 2x2 spatial (wr,wc) x 2 K-halves
//   (kh). Wave tile 64x64 = 2x2 of 32x32 frags, acc f32x16[2][2].
//   32x32x16 vs 16x16x32: same FLOP/bytes, HALF the ds_read_b128 and MFMA
//   instruction count (8+8 vs 16+16 per wave/tile) -- LDS reads are
//   instruction-bound (~12cy/b128, m134), so this halves the LDS-issue time
//   that the per-tile barrier serializes against MFMA.
//   Frag maps: A/B row=lane&31, K-half=lane>>5 (8 elems);
//   C/D col=lane&31, row=(reg&3)+8*(reg>>2)+4*(lane>>5) [m74/m101].
//   Staging/pipeline/swizzles/vmcnt identical to R7 (verified):
//   gload_lds, 3 buffers, depth 2, steady vmcnt(6/4), XOR swizzles
//   (fp32 A: 16B-chunk ^(row&15); bf16: 16B-grp ^(row&7)), XCD remap.
//   TA=1: A raw fp32 (x), frags packed via v_cvt_pk_bf16_f32. LDS 144KB.
//   TA=0: A bf16 per-tile src switch (t<tsplit ? Ab0 : Ab1). LDS 96KB.
// OUT_MODE 0: bf16 store. OUT_MODE 1: f32 store + bias[col].
// ---------------------------------------------------------------------------
template <int TA, int OUT_MODE>
__global__ __launch_bounds__(512, 2) void gemm_f(
    const float* __restrict__ Af,
    const unsigned short* __restrict__ Ab0, const unsigned short* __restrict__ Ab1,
    int tsplit,
    const unsigned short* __restrict__ BT,
    unsigned short* __restrict__ Cb, float* __restrict__ Cf,
    const float* __restrict__ bias)
{
    constexpr int ABUF = TA ? 49152 : 32768;   // bytes per buffer (A+B)
    constexpr int ABYT = TA ? 32768 : 16384;   // A bytes within buffer
    __shared__ uint8_t sh[3 * ABUF];

    // XCD-aware remap (256 blocks, %8==0 -> bijective chunked).
    int orig = blockIdx.y * 8 + blockIdx.x;
    int wg   = (orig & 7) * 32 + (orig >> 3);
    const int m0 = (wg >> 3) * 128, n0 = (wg & 7) * 128;

    const int tid  = threadIdx.x;
    const int wid  = tid >> 6;
    const int lane = tid & 63;
    const int wr   = wid >> 2;
    const int wc   = (wid >> 1) & 1;
    const int kh   = wid & 1;
    const int l31  = lane & 31, hi = lane >> 5;

    f32x16 acc[2][2] = {};

    auto stage = [&](int buf, int t) {
        uint8_t* Abase = sh + buf * ABUF;
        uint8_t* Bbase = Abase + ABYT;
        if (TA) {
            const float* Asrc = Af + (size_t)m0 * EDIM + t * 64;
#pragma unroll
            for (int j = 0; j < 4; ++j) {
                int slot = j * 512 + tid;
                int row = slot >> 4, c = (slot & 15) ^ (row & 15);
                lds16(Asrc + (size_t)row * EDIM + c * 4,
                      Abase + j * 8192 + wid * 1024);
            }
        } else {
            const unsigned short* Asrc =
                (t < tsplit ? Ab0 : Ab1) + (size_t)m0 * EDIM + t * 64;
#pragma unroll
            for (int j = 0; j < 2; ++j) {
                int slot = j * 512 + tid;
                int row = slot >> 3, c = (slot & 7) ^ (row & 7);
                lds16(Asrc + (size_t)row * EDIM + c * 8,
                      Abase + j * 8192 + wid * 1024);
            }
        }
        const unsigned short* Bsrc = BT + (size_t)n0 * EDIM + t * 64;
#pragma unroll
        for (int j = 0; j < 2; ++j) {
            int slot = j * 512 + tid;
            int row = slot >> 3, c = (slot & 7) ^ (row & 7);
            lds16(Bsrc + (size_t)row * EDIM + c * 8,
                  Bbase + j * 8192 + wid * 1024);
        }
    };

    auto compute = [&](int buf) {
        const uint8_t* Abase = sh + buf * ABUF;
        const unsigned short* bs = (const unsigned short*)(Abase + ABYT);
#pragma unroll
        for (int s = 0; s < 2; ++s) {                  // two K=16 slabs
            bf16x8 a[2], b[2];
#pragma unroll
            for (int mi = 0; mi < 2; ++mi) {
                int row = wr * 64 + mi * 32 + l31;
                if (TA) {
                    const float* as = (const float*)Abase;
                    int c0 = kh * 8 + s * 4 + hi * 2;
                    f32x4 lo = *(const f32x4*)(as + row * 64 + ((c0 ^ (row & 15)) * 4));
                    f32x4 h4 = *(const f32x4*)(as + row * 64 + (((c0 + 1) ^ (row & 15)) * 4));
                    union { unsigned u[4]; bf16x8 v; } fu;
                    fu.u[0] = cvtpk(lo[0], lo[1]); fu.u[1] = cvtpk(lo[2], lo[3]);
                    fu.u[2] = cvtpk(h4[0], h4[1]); fu.u[3] = cvtpk(h4[2], h4[3]);
                    a[mi] = fu.v;
                } else {
                    const unsigned short* as = (const unsigned short*)Abase;
                    int cg = kh * 4 + s * 2 + hi;
                    a[mi] = *(const bf16x8*)(as + row * 64 + ((cg ^ (row & 7)) * 8));
                }
            }
#pragma unroll
            for (int ni = 0; ni < 2; ++ni) {
                int row = wc * 64 + ni * 32 + l31;
                int cg = kh * 4 + s * 2 + hi;
                b[ni] = *(const bf16x8*)(bs + row * 64 + ((cg ^ (row & 7)) * 8));
            }
#pragma unroll
            for (int mi = 0; mi < 2; ++mi)
#pragma unroll
                for (int ni = 0; ni < 2; ++ni)
                    acc[mi][ni] = __builtin_amdgcn_mfma_f32_32x32x16_bf16(a[mi], b[ni], acc[mi][ni], 0, 0, 0);
        }
    };

    const int NT = EDIM >> 6;   // 16 K-tiles
    stage(0, 0);
    stage(1, 1);
    if (TA) asm volatile("s_waitcnt vmcnt(6)" ::: "memory");   // tile 0 landed
    else    asm volatile("s_waitcnt vmcnt(4)" ::: "memory");
    __builtin_amdgcn_s_barrier();
    asm volatile("" ::: "memory");

    for (int t = 0; t < NT; ++t) {
        if (t + 2 < NT) stage((t + 2) % 3, t + 2);
        compute(t % 3);
        if (t + 1 < NT) {
            if (t + 2 < NT) {
                if (TA) asm volatile("s_waitcnt vmcnt(6)" ::: "memory");
                else    asm volatile("s_waitcnt vmcnt(4)" ::: "memory");
            } else {
                asm volatile("s_waitcnt vmcnt(0)" ::: "memory");   // drain tail
            }
            __builtin_amdgcn_s_barrier();
            asm volatile("" ::: "memory");
        }
    }

    // ---- K-split merge: kh=1 dumps partials to LDS, kh=0 adds & stores. ----
    // acc element i of frag (mi,ni): col = ni*32+l31,
    // row (within 64x64 tile) = mi*32 + 8*(i>>2) + 4*hi + (i&3)  [m74/m101].
    // Mg per-quadrant [col][rowgrp] f32x4, bank-staggered grp^(col&15).
    __syncthreads();   // all MFMA reads of sh complete before overwrite
    float* Mg = (float*)sh;            // 64KB needed
    const int mgbase = (wr * 2 + wc) * 4096;
    if (kh) {
#pragma unroll
        for (int mi = 0; mi < 2; ++mi)
#pragma unroll
            for (int ni = 0; ni < 2; ++ni) {
                int col = ni * 32 + l31;
#pragma unroll
                for (int q = 0; q < 4; ++q) {
                    int grp = mi * 8 + 2 * q + hi;
                    int adr = mgbase + col * 64 + (((grp) ^ (col & 15)) << 2);
                    f32x4 v;
                    v[0] = acc[mi][ni][q * 4 + 0]; v[1] = acc[mi][ni][q * 4 + 1];
                    v[2] = acc[mi][ni][q * 4 + 2]; v[3] = acc[mi][ni][q * 4 + 3];
                    *(f32x4*)(Mg + adr) = v;
                }
            }
    }
    __syncthreads();
    if (!kh) {
#pragma unroll
        for (int mi = 0; mi < 2; ++mi) {
#pragma unroll
            for (int ni = 0; ni < 2; ++ni) {
                int col = ni * 32 + l31;
                int gcol = n0 + wc * 64 + col;
#pragma unroll
                for (int q = 0; q < 4; ++q) {
                    int grp = mi * 8 + 2 * q + hi;
                    int adr = mgbase + col * 64 + (((grp) ^ (col & 15)) << 2);
                    f32x4 p = *(const f32x4*)(Mg + adr);
                    int rowb = m0 + wr * 64 + mi * 32 + 8 * q + 4 * hi;
#pragma unroll
                    for (int j = 0; j < 4; ++j) {
                        float v = acc[mi][ni][q * 4 + j] + p[j];
                        if (OUT_MODE == 0) {
                            Cb[(size_t)(rowb + j) * EDIM + gcol] = f2b(v);
                        } else {
                            Cf[(size_t)(rowb + j) * EDIM + gcol] = v + bias[gcol];
                        }
                    }
                }
            }
        }
    }
}

// ---------------------------------------------------------------------------
// conv: causal FIR on cols 256..1023 (v0 cols read from T by gemm2's t<4
// tiles). Thread: 4 channels x 2 consecutive positions.  (R7-verified)
// ---------------------------------------------------------------------------
__global__ __launch_bounds__(256) void conv_kernel(
    const unsigned short* __restrict__ T, unsigned short* __restrict__ V,
    const float* __restrict__ H, const float* __restrict__ Beff,
    const float* __restrict__ Corr)
{
    unsigned w  = blockIdx.x * 256 + threadIdx.x;   // 2048 rowpairs x 192 quads
    unsigned rp = w / 192u;
    int c4 = (int)(w - rp * 192u);
    int m  = (int)rp * 2;                           // pair never crosses batch
    int ch = c4 * 4;                                // [0,768)
    int e0 = 256 + ch;
    const unsigned short* tp = T + (size_t)m * EDIM + e0;
    unsigned short*       vp = V + (size_t)m * EDIM + e0;
    int l  = m & (L_SEQ - 1);
    float4v b4 = *(const float4v*)(Beff + ch);
    float4v acc0 = b4, acc1 = b4;

    {
        float4v h = *(const float4v*)(H + ch);      // H[0], row m+1
        us4 t = *(const us4*)(tp + EDIM);
        acc1[0] += h[0] * b2f(t[0]); acc1[1] += h[1] * b2f(t[1]);
        acc1[2] += h[2] * b2f(t[2]); acc1[3] += h[3] * b2f(t[3]);
    }
    int ni = (l < 12) ? l : 12;
    for (int i = 0; i <= ni; ++i) {                 // row m-i, taps h[i]/h[i+1]
        us4 t = *(const us4*)(tp - (size_t)i * EDIM);
        float4v h0 = *(const float4v*)(H + i * 768 + ch);
        acc0[0] += h0[0] * b2f(t[0]); acc0[1] += h0[1] * b2f(t[1]);
        acc0[2] += h0[2] * b2f(t[2]); acc0[3] += h0[3] * b2f(t[3]);
        if (i < 12) {
            float4v h1 = *(const float4v*)(H + (i + 1) * 768 + ch);
            acc1[0] += h1[0] * b2f(t[0]); acc1[1] += h1[1] * b2f(t[1]);
            acc1[2] += h1[2] * b2f(t[2]); acc1[3] += h1[3] * b2f(t[3]);
        }
    }
    if (l < 6) {   // bias boundary correction (intermediate zero-padding)
        float4v c = *(const float4v*)(Corr + l * 768 + ch);
        acc0[0] -= c[0]; acc0[1] -= c[1]; acc0[2] -= c[2]; acc0[3] -= c[3];
    }
    if (l + 1 < 6) {
        float4v c = *(const float4v*)(Corr + (l + 1) * 768 + ch);
        acc1[0] -= c[0]; acc1[1] -= c[1]; acc1[2] -= c[2]; acc1[3] -= c[3];
    }
    us4 o0, o1;
    o0[0] = f2b(acc0[0]); o0[1] = f2b(acc0[1]); o0[2] = f2b(acc0[2]); o0[3] = f2b(acc0[3]);
    o1[0] = f2b(acc1[0]); o1[1] = f2b(acc1[1]); o1[2] = f2b(acc1[2]); o1[3] = f2b(acc1[3]);
    *(us4*)vp = o0;
    *(us4*)(vp + EDIM) = o1;
}

// ---------------------------------------------------------------------------
extern "C" void kernel_launch(void* const* d_in, const int* in_sizes, int n_in,
                              void* d_out, int out_size, void* d_ws, size_t ws_size,
                              hipStream_t stream)
{
    const float* x  = (const float*)d_in[0];
    const float* Wq = (const float*)d_in[1];
    // d_in[2] = Wk (dead: attention output is multiplied by 0.0)
    const float* Wv = (const float*)d_in[3];
    const float* Wo = (const float*)d_in[4];
    const float* bo = (const float*)d_in[5];

    uint8_t* ws = (uint8_t*)d_ws;
    unsigned short* W1b = (unsigned short*)(ws);                    //  2 MB
    unsigned short* Wob = (unsigned short*)(ws + (2u  << 20));      //  2 MB
    unsigned short* T   = (unsigned short*)(ws + (4u  << 20));      //  8 MB
    unsigned short* V   = (unsigned short*)(ws + (12u << 20));      //  8 MB
    float* H    = (float*)(ws + (20u << 20));                        // 40 KB
    float* Beff = (float*)(ws + (20u << 20) + (64u << 10));          //  3 KB
    float* Corr = (float*)(ws + (20u << 20) + (96u << 10));          // 18 KB

    wprep_kernel<<<2051, 256, 0, stream>>>(
        Wq, Wv, Wo, W1b, Wob,
        (const float*)d_in[6],  (const float*)d_in[7],
        (const float*)d_in[10], (const float*)d_in[11],
        (const float*)d_in[12], (const float*)d_in[13],
        (const float*)d_in[16], (const float*)d_in[17],
        (const float*)d_in[18], (const float*)d_in[19],
        (const float*)d_in[22], (const float*)d_in[23],
        H, Beff, Corr);

    dim3 gg(EDIM / 128, MTOT / 128);   // (8, 32) = 256 blocks
    // gemm1: T = x @ W1^T, A read as raw fp32 (prep fused away)
    gemm_f<1, 0><<<gg, 512, 0, stream>>>(x, nullptr, nullptr, 0,
                                         W1b, T, nullptr, nullptr);

    conv_kernel<<<1536, 256, 0, stream>>>(T, V, H, Beff, Corr);

    // gemm2: out = [T[:, :256] | V[:, 256:]] @ Wo^T + bo  (tsplit=4 tiles)
    gemm_f<0, 1><<<gg, 512, 0, stream>>>(nullptr, T, V, 4,
                                         Wob, nullptr, (float*)d_out, bo);
}